// Round 6
// baseline (272.843 us; speedup 1.0000x reference)
//
#include <hip/hip_runtime.h>

#define BC 4096      // rows of hidden_current
#define BP 8192      // rows of hidden_previous
#define D  768
#define KNB 5
#define TOPK 6
#define NT (BP / 128)   // 64 column tiles of the similarity matrix

typedef __bf16 bf16x8 __attribute__((ext_vector_type(8)));
typedef float  f32x4  __attribute__((ext_vector_type(4)));

__device__ __forceinline__ unsigned short f2bf(float f) {
    unsigned int u = __float_as_uint(f);
    u += 0x7fffu + ((u >> 16) & 1u);          // round-to-nearest-even
    return (unsigned short)(u >> 16);
}

__device__ __forceinline__ void gload16(const void* g, void* l) {
    __builtin_amdgcn_global_load_lds(
        (const __attribute__((address_space(1))) unsigned int*)g,
        (__attribute__((address_space(3))) unsigned int*)l, 16, 0, 0);
}

// Float+int insertion network — used by k_mergeloss (global merge, exact indices).
__device__ __forceinline__ void topk_insert(float v, int j, float* bv, int* bj) {
    #pragma unroll
    for (int q = TOPK - 1; q >= 1; q--) {
        bool up   = v > bv[q - 1];
        bool here = (v > bv[q]) && !up;
        bv[q] = up ? bv[q - 1] : (here ? v : bv[q]);
        bj[q] = up ? bj[q - 1] : (here ? j : bj[q]);
    }
    if (v > bv[0]) { bv[0] = v; bj[0] = j; }
}

// Packed-key bubble insert (r17): bk[] sorted DESCENDING; one pass of pure
// v_max_u32/v_min_u32 (12 VOP2 ops, no cndmask). Keys unique (packed col bits).
__device__ __forceinline__ void topk_insert_u(unsigned v, unsigned* bk) {
    unsigned c = v;
    #pragma unroll
    for (int q = 0; q < TOPK; q++) {
        unsigned hi = (c > bk[q]) ? c : bk[q];   // v_max_u32
        c           = (c > bk[q]) ? bk[q] : c;   // v_min_u32
        bk[q] = hi;
    }
}

// ---------------- fused normalize: hp -> bf16 ranking copy, hc -> fp32 + sq ------
// UNCHANGED (bit-identical outputs). hpnb is PRE-SWIZZLED: element e of row r
// stored at e ^ ((r&7)<<3) so monotone global_load_lds staging lands the
// XOR-swizzled LDS layout for free -> conflict-free fragment ds_read_b128.
__global__ __launch_bounds__(256) void k_norm(const float* __restrict__ hp,
                                              const float* __restrict__ hc,
                                              unsigned short* __restrict__ hpnb,
                                              float* __restrict__ hcn,
                                              float* __restrict__ sqout,
                                              float* __restrict__ out) {
    int b = blockIdx.x;
    int t = threadIdx.x;
    if (b == 0 && t == 0) out[0] = 0.0f;
    bool isP = (b < BP);
    int row = isP ? b : (b - BP);
    const float* xr = (isP ? hp : hc) + (size_t)row * D;
    float v0 = xr[t], v1 = xr[t + 256], v2 = xr[t + 512];
    float s = v0 * v0 + v1 * v1 + v2 * v2;
    #pragma unroll
    for (int off = 32; off; off >>= 1) s += __shfl_xor(s, off, 64);
    __shared__ float wsum[4];
    if ((t & 63) == 0) wsum[t >> 6] = s;
    __syncthreads();
    float tot = wsum[0] + wsum[1] + wsum[2] + wsum[3];
    float rinv = 1.0f / fmaxf(sqrtf(tot), 1e-12f);
    if (isP) {
        unsigned short* yr = hpnb + (size_t)row * D;
        int rx = (row & 7) << 3;                       // chunk swizzle (bits 3..5)
        yr[t ^ rx]         = f2bf(v0 * rinv);
        yr[(t + 256) ^ rx] = f2bf(v1 * rinv);
        yr[(t + 512) ^ rx] = f2bf(v2 * rinv);
    } else {
        float* yr = hcn + (size_t)row * D;
        yr[t] = v0 * rinv; yr[t + 256] = v1 * rinv; yr[t + 512] = v2 * rinv;
        if (t == 0) sqout[row] = tot * rinv * rinv;
    }
}

// ---------------- bf16 MFMA similarity tile + fused per-row top-6 ----------------
// r21: REVERT to the proven r17 structure (full 2048-tile grid, homogeneous
// blocks — the symmetry-skip variants r19/r20 lost more to epilogue
// serialization + ragged 1.5-generation tails than the 24% work cut gained),
// PLUS a 5th block/CU via LDS diet 36864 -> 32768:
//   - score buffer is UNPADDED u32[128][64] with XOR swizzle slot = col^(row&31).
//     Dump writes swizzled; scan reads slots in per-lane XOR order (2-way bank
//     = free). No de-swizzle needed: the column is embedded in the key's low
//     7 bits, and top-6 of a permuted set is bit-identical (keys unique).
//     Dump stores become 4-way conflicted (quad/l15 preimage collapse) — tiny
//     vs the scan. Merge buffer mk aliases the dead score region post-barrier.
//   - 5 x 32768 = exactly the 160 KB LDS pool -> +25% co-resident blocks, more
//     phase drift to hide the per-K-step barrier drain (the ~30% idle time:
//     MfmaUtil 35.6 + VALUBusy 34 + nothing-else at r17).
__global__ __launch_bounds__(256, 5) void k_simtop(const unsigned short* __restrict__ hp,
                                                   float* __restrict__ candv,
                                                   int* __restrict__ candi) {
    __shared__ char smem[32768];
    unsigned short* sA = (unsigned short*)smem;          // [128 rows][64 k] swizzled
    unsigned short* sB = sA + 128 * 64;
    unsigned* sK = (unsigned*)smem;                      // [128][64] packed keys (alias)
    unsigned* mk = (unsigned*)smem;                      // [128][7] merge lists (alias,
                                                         //  used only after sS is dead)

    const int t = threadIdx.x;
    const int l = t & 63;
    const int w = t >> 6;
    const int l15 = l & 15, quad = l >> 4;
    const int wr = w >> 1, wc = w & 1;

    // super-tile swizzle (r15): xcd = b&7; 8x8-tile supers on the 32x64 grid
    // (A+B panels 3.1 MB < 4 MB per-XCD L2 -> FETCH ~29 MB).
    int ri, ci;
    {
        int b = blockIdx.x;
        int super_id = (((b >> 9) & 3) << 3) | (b & 7);  // 0..31
        int within = (b >> 3) & 63;                       // 0..63
        ri = (super_id >> 3) * 8 + (within >> 3);         // 0..31
        ci = (super_id & 7) * 8 + (within & 7);           // 0..63
    }

    // per-lane global source: row group w*32 + p*8 + (l>>3), chunk l&7 (monotone)
    const int srow = l >> 3, sch = l & 7;
    const unsigned short* Ag = hp + (size_t)(ri * 128 + w * 32 + srow) * D + sch * 8;
    const unsigned short* Bg = hp + (size_t)(ci * 128 + w * 32 + srow) * D + sch * 8;
    unsigned short* la = sA + (w * 32) * 64;             // wave-uniform LDS bases
    unsigned short* lb = sB + (w * 32) * 64;

    // C-init = +4.0 bias: scores positive -> raw bits unsigned-compare monotone.
    f32x4 acc[4][4];
    #pragma unroll
    for (int i = 0; i < 4; i++)
        #pragma unroll
        for (int j = 0; j < 4; j++) acc[i][j] = (f32x4){4.f, 4.f, 4.f, 4.f};

    // fragment LDS chunk offsets (conflict-free): original k-chunk q of row r
    // sits at LDS pos q^(r&7); frag rows have r&7 == l15&7.
    const int x7  = l15 & 7;
    const int ch0 = (quad ^ x7) * 16;
    const int ch1 = ((quad + 4) ^ x7) * 16;

    for (int kk = 0; kk < D; kk += 64) {
        __syncthreads();                                 // prev iter's LDS reads done
        #pragma unroll
        for (int p = 0; p < 4; p++) {
            gload16(Ag + (size_t)(p * 8) * D + kk, la + (p * 8) * 64);
            gload16(Bg + (size_t)(p * 8) * D + kk, lb + (p * 8) * 64);
        }
        __syncthreads();                                 // vmcnt drain + tile ready
        #pragma unroll
        for (int ks = 0; ks < 2; ks++) {
            const int ch = ks ? ch1 : ch0;
            bf16x8 af[4], bfr[4];
            #pragma unroll
            for (int mi = 0; mi < 4; mi++)
                af[mi] = *(const bf16x8*)((const char*)sA + (wr * 64 + mi * 16 + l15) * 128 + ch);
            #pragma unroll
            for (int ni = 0; ni < 4; ni++)
                bfr[ni] = *(const bf16x8*)((const char*)sB + (wc * 64 + ni * 16 + l15) * 128 + ch);
            __builtin_amdgcn_s_setprio(1);
            #pragma unroll
            for (int mi = 0; mi < 4; mi++)
                #pragma unroll
                for (int ni = 0; ni < 4; ni++)
                    acc[mi][ni] = __builtin_amdgcn_mfma_f32_16x16x32_bf16(af[mi], bfr[ni], acc[mi][ni], 0, 0, 0);
            __builtin_amdgcn_s_setprio(0);
        }
    }

    // epilogue: 2 dump phases of 64 cols; 256 threads scan 2-per-row (32 cols each)
    unsigned bk[TOPK];
    #pragma unroll
    for (int s = 0; s < TOPK; s++) bk[s] = 0u;

    const int erow = t & 127, scb = (t >> 7) * 32;
    const int erx = erow & 31;                           // scan de-conflict XOR
    #pragma unroll
    for (int h = 0; h < 2; h++) {
        __syncthreads();
        if (wc == h) {
            #pragma unroll
            for (int ni = 0; ni < 4; ni++) {
                // inverted in-tile col -> quantized ties prefer SMALLER index
                unsigned pk = (unsigned)(127 - h * 64 - ni * 16 - l15);
                #pragma unroll
                for (int mi = 0; mi < 4; mi++) {
                    int colb = ni * 16 + l15;
                    int rowb = wr * 64 + mi * 16 + quad * 4;
                    f32x4 v = acc[mi][ni];
                    #pragma unroll
                    for (int r = 0; r < 4; r++) {  // swizzled slot: col ^ (row&31)
                        int rowg = rowb + r;
                        sK[rowg * 64 + (colb ^ (rowg & 31))] =
                            (__float_as_uint(v[r]) & 0xFFFFFF80u) | pk;
                    }
                }
            }
        }
        __syncthreads();
        // scan slots in per-lane XOR order: banks spread (2-way = free), and the
        // permutation is harmless — the key embeds the column; top-6 of the same
        // set is bit-identical.
        const unsigned* rowp = sK + erow * 64 + scb;
        #pragma unroll
        for (int c = 0; c < 32; c++) topk_insert_u(rowp[c ^ erx], bk);
    }

    // merge the two half-row scanners (mk aliases the dead score buffer;
    // stride 7 -> conflict-free)
    __syncthreads();
    if (t >= 128) {
        #pragma unroll
        for (int s = 0; s < TOPK; s++) mk[(t - 128) * 7 + s] = bk[s];
    }
    __syncthreads();
    if (t < 128) {
        #pragma unroll
        for (int s0 = 0; s0 < TOPK; s0++) topk_insert_u(mk[t * 7 + s0], bk);
        size_t o = ((size_t)(ri * 128 + t) * NT + ci) * TOPK;
        #pragma unroll
        for (int s = 0; s < TOPK; s++) {
            unsigned k = bk[s];
            candv[o + s] = __uint_as_float(k & 0xFFFFFF80u);   // quantized biased score
            candi[o + s] = ci * 128 + 127 - (int)(k & 127u);   // global column
        }
    }
}

// ------- fused merge (wave-parallel) + sparse loss + global atomic accumulate ----
// Unchanged from r17.
__global__ __launch_bounds__(256) void k_mergeloss(const float* __restrict__ candv,
                                                   const int* __restrict__ candi,
                                                   const float* __restrict__ hcn,
                                                   const float* __restrict__ sq,
                                                   const int* __restrict__ labp,
                                                   float* __restrict__ out) {
    __shared__ float bsum[4];
    const int w = threadIdx.x >> 6, lane = threadIdx.x & 63;
    const int i = blockIdx.x * 4 + w;

    const float* cv = candv + ((size_t)i * NT + lane) * TOPK;
    const int*   cj = candi + ((size_t)i * NT + lane) * TOPK;
    float bv[TOPK]; int bj[TOPK];
    #pragma unroll
    for (int s = 0; s < TOPK; s++) { bv[s] = cv[s]; bj[s] = cj[s]; }

    #pragma unroll
    for (int off = 1; off < 64; off <<= 1) {
        float pv[TOPK]; int pj[TOPK];
        #pragma unroll
        for (int s = 0; s < TOPK; s++) {
            pv[s] = __shfl_xor(bv[s], off, 64);
            pj[s] = __shfl_xor(bj[s], off, 64);
        }
        bool ilow = (lane & off) == 0;
        float av[TOPK], iv[TOPK]; int aj[TOPK], ij[TOPK];
        #pragma unroll
        for (int s = 0; s < TOPK; s++) {
            av[s] = ilow ? bv[s] : pv[s];  aj[s] = ilow ? bj[s] : pj[s];
            iv[s] = ilow ? pv[s] : bv[s];  ij[s] = ilow ? pj[s] : bj[s];
        }
        #pragma unroll
        for (int s = 0; s < TOPK; s++)
            if (iv[s] > av[TOPK - 1]) topk_insert(iv[s], ij[s], av, aj);
        #pragma unroll
        for (int s = 0; s < TOPK; s++) { bv[s] = av[s]; bj[s] = aj[s]; }
    }

    // loss: ranks 1..5 (rank 0 is self — biased self-score 5.0 is still max).
    const float* hi = hcn + (size_t)i * D;
    float4 h0 = *(const float4*)(hi + lane * 4);
    float4 h1 = *(const float4*)(hi + lane * 4 + 256);
    float4 h2 = *(const float4*)(hi + lane * 4 + 512);
    float sqi = sq[i];
    int li = labp[i];
    float part = 0.f;
    float base = 0.f;
    #pragma unroll
    for (int s = 1; s <= KNB; s++) {
        int j = bj[s];
        if (j >= BC) continue;
        const float* hj = hcn + (size_t)j * D;
        float4 g0 = *(const float4*)(hj + lane * 4);
        float4 g1 = *(const float4*)(hj + lane * 4 + 256);
        float4 g2 = *(const float4*)(hj + lane * 4 + 512);
        float d = h0.x * g0.x + h0.y * g0.y + h0.z * g0.z + h0.w * g0.w
                + h1.x * g1.x + h1.y * g1.y + h1.z * g1.z + h1.w * g1.w
                + h2.x * g2.x + h2.y * g2.y + h2.z * g2.z + h2.w * g2.w;
        float e = (li == labp[j]) ? 1.0f : -1.0f;
        part += e * (-2.0f) * d;
        if (lane == 0) base += e * (sqi + sq[j]);
    }
    part += base;
    #pragma unroll
    for (int off = 32; off; off >>= 1) part += __shfl_xor(part, off, 64);
    if (lane == 0) bsum[w] = part;
    __syncthreads();
    if (threadIdx.x == 0) {
        float s = bsum[0] + bsum[1] + bsum[2] + bsum[3];
        unsafeAtomicAdd(out, 0.5f * s / ((float)BC * (float)BC));
    }
}

extern "C" void kernel_launch(void* const* d_in, const int* in_sizes, int n_in,
                              void* d_out, int out_size, void* d_ws, size_t ws_size,
                              hipStream_t stream) {
    const float* hc   = (const float*)d_in[0];  // hidden_current  (4096,768)
    const float* hp   = (const float*)d_in[1];  // hidden_previous (8192,768)
    const int*   labp = (const int*)d_in[3];    // labels_previous (8192,)
    float* out = (float*)d_out;

    // workspace layout (~38 MB)
    unsigned short* hpnb = (unsigned short*)d_ws;          // BP*D bf16 (pre-swizzled)
    float* hcn  = (float*)(hpnb + (size_t)BP * D);         // BC*D f32
    float* sq   = hcn + (size_t)BC * D;                    // BC
    float* candv = sq + BC;                                // BC*NT*TOPK
    int*   candi = (int*)(candv + (size_t)BC * NT * TOPK); // BC*NT*TOPK

    k_norm<<<dim3(BP + BC), dim3(256), 0, stream>>>(hp, hc, hpnb, hcn, sq, out);
    k_simtop<<<dim3(2048), dim3(256), 0, stream>>>(hpnb, candv, candi);
    k_mergeloss<<<dim3(BC / 4), dim3(256), 0, stream>>>(candv, candi, hcn, sq, labp, out);
}

// Round 7
// 166.083 us; speedup vs baseline: 1.6428x; 1.6428x over previous
//
#include <hip/hip_runtime.h>

#define BC 4096      // rows of hidden_current
#define BP 8192      // rows of hidden_previous
#define D  768
#define KNB 5
#define TOPK 6
#define NT (BP / 128)   // 64 column tiles of the similarity matrix

typedef __bf16 bf16x8 __attribute__((ext_vector_type(8)));
typedef float  f32x4  __attribute__((ext_vector_type(4)));

__device__ __forceinline__ unsigned short f2bf(float f) {
    unsigned int u = __float_as_uint(f);
    u += 0x7fffu + ((u >> 16) & 1u);          // round-to-nearest-even
    return (unsigned short)(u >> 16);
}

__device__ __forceinline__ void gload16(const void* g, void* l) {
    __builtin_amdgcn_global_load_lds(
        (const __attribute__((address_space(1))) unsigned int*)g,
        (__attribute__((address_space(3))) unsigned int*)l, 16, 0, 0);
}

// Float+int insertion network — used by k_mergeloss (global merge, exact indices).
__device__ __forceinline__ void topk_insert(float v, int j, float* bv, int* bj) {
    #pragma unroll
    for (int q = TOPK - 1; q >= 1; q--) {
        bool up   = v > bv[q - 1];
        bool here = (v > bv[q]) && !up;
        bv[q] = up ? bv[q - 1] : (here ? v : bv[q]);
        bj[q] = up ? bj[q - 1] : (here ? j : bj[q]);
    }
    if (v > bv[0]) { bv[0] = v; bj[0] = j; }
}

// Packed-key bubble insert (r17): bk[] sorted DESCENDING; one pass of pure
// v_max_u32/v_min_u32 (12 VOP2 ops, no cndmask). Keys unique (packed col bits).
__device__ __forceinline__ void topk_insert_u(unsigned v, unsigned* bk) {
    unsigned c = v;
    #pragma unroll
    for (int q = 0; q < TOPK; q++) {
        unsigned hi = (c > bk[q]) ? c : bk[q];   // v_max_u32
        c           = (c > bk[q]) ? bk[q] : c;   // v_min_u32
        bk[q] = hi;
    }
}

// ---------------- fused normalize: hp -> bf16 ranking copy, hc -> fp32 + sq ------
// UNCHANGED (bit-identical outputs). hpnb is PRE-SWIZZLED: element e of row r
// stored at e ^ ((r&7)<<3) so monotone global_load_lds staging lands the
// XOR-swizzled LDS layout for free -> conflict-free fragment ds_read_b128.
__global__ __launch_bounds__(256) void k_norm(const float* __restrict__ hp,
                                              const float* __restrict__ hc,
                                              unsigned short* __restrict__ hpnb,
                                              float* __restrict__ hcn,
                                              float* __restrict__ sqout,
                                              float* __restrict__ out) {
    int b = blockIdx.x;
    int t = threadIdx.x;
    if (b == 0 && t == 0) out[0] = 0.0f;
    bool isP = (b < BP);
    int row = isP ? b : (b - BP);
    const float* xr = (isP ? hp : hc) + (size_t)row * D;
    float v0 = xr[t], v1 = xr[t + 256], v2 = xr[t + 512];
    float s = v0 * v0 + v1 * v1 + v2 * v2;
    #pragma unroll
    for (int off = 32; off; off >>= 1) s += __shfl_xor(s, off, 64);
    __shared__ float wsum[4];
    if ((t & 63) == 0) wsum[t >> 6] = s;
    __syncthreads();
    float tot = wsum[0] + wsum[1] + wsum[2] + wsum[3];
    float rinv = 1.0f / fmaxf(sqrtf(tot), 1e-12f);
    if (isP) {
        unsigned short* yr = hpnb + (size_t)row * D;
        int rx = (row & 7) << 3;                       // chunk swizzle (bits 3..5)
        yr[t ^ rx]         = f2bf(v0 * rinv);
        yr[(t + 256) ^ rx] = f2bf(v1 * rinv);
        yr[(t + 512) ^ rx] = f2bf(v2 * rinv);
    } else {
        float* yr = hcn + (size_t)row * D;
        yr[t] = v0 * rinv; yr[t + 256] = v1 * rinv; yr[t + 512] = v2 * rinv;
        if (t == 0) sqout[row] = tot * rinv * rinv;
    }
}

// ---------------- bf16 MFMA similarity tile + fused per-row top-6 ----------------
// r22: r21's 32 KB LDS diet (unpadded XOR-swizzled score buffer, aliased merge
// buffer) with the occupancy pragma FIXED. r21's __launch_bounds__(256,5)
// capped the register allocator below the kernel's ~110-VGPR need -> compiler
// emitted 48 VGPRs + scratch-spilled the accumulators (WRITE_SIZE 12->392 MB,
// MfmaUtil 35.6->11.3, 181 us). (256,4) restores the proven 60-VGPR no-spill
// codegen; 60 VGPR supports 8 waves/SIMD, so the RUNTIME can still co-schedule
// the 5th block/CU that the 32 KB footprint allows (5 x 32768 = 160 KiB pool).
// Worst case the 5th block is refused and this is exactly r17 (61.5 us).
//   - score buffer: unpadded u32[128][64], slot = col ^ (row&31). Dump writes
//     swizzled (4-way conflict, tiny); scan reads in per-lane XOR order (2-way,
//     free). No de-swizzle: the column lives in the key's low 7 bits and top-6
//     of a permuted set is bit-identical (keys unique).
//   - merge buffer mk aliases the dead score region after the last scan.
__global__ __launch_bounds__(256, 4) void k_simtop(const unsigned short* __restrict__ hp,
                                                   float* __restrict__ candv,
                                                   int* __restrict__ candi) {
    __shared__ char smem[32768];
    unsigned short* sA = (unsigned short*)smem;          // [128 rows][64 k] swizzled
    unsigned short* sB = sA + 128 * 64;
    unsigned* sK = (unsigned*)smem;                      // [128][64] packed keys (alias)
    unsigned* mk = (unsigned*)smem;                      // [128][7] merge lists (alias,
                                                         //  used only after sK is dead)

    const int t = threadIdx.x;
    const int l = t & 63;
    const int w = t >> 6;
    const int l15 = l & 15, quad = l >> 4;
    const int wr = w >> 1, wc = w & 1;

    // super-tile swizzle (r15): xcd = b&7; 8x8-tile supers on the 32x64 grid
    // (A+B panels 3.1 MB < 4 MB per-XCD L2 -> FETCH ~29 MB).
    int ri, ci;
    {
        int b = blockIdx.x;
        int super_id = (((b >> 9) & 3) << 3) | (b & 7);  // 0..31
        int within = (b >> 3) & 63;                       // 0..63
        ri = (super_id >> 3) * 8 + (within >> 3);         // 0..31
        ci = (super_id & 7) * 8 + (within & 7);           // 0..63
    }

    // per-lane global source: row group w*32 + p*8 + (l>>3), chunk l&7 (monotone)
    const int srow = l >> 3, sch = l & 7;
    const unsigned short* Ag = hp + (size_t)(ri * 128 + w * 32 + srow) * D + sch * 8;
    const unsigned short* Bg = hp + (size_t)(ci * 128 + w * 32 + srow) * D + sch * 8;
    unsigned short* la = sA + (w * 32) * 64;             // wave-uniform LDS bases
    unsigned short* lb = sB + (w * 32) * 64;

    // C-init = +4.0 bias: scores positive -> raw bits unsigned-compare monotone.
    f32x4 acc[4][4];
    #pragma unroll
    for (int i = 0; i < 4; i++)
        #pragma unroll
        for (int j = 0; j < 4; j++) acc[i][j] = (f32x4){4.f, 4.f, 4.f, 4.f};

    // fragment LDS chunk offsets (conflict-free): original k-chunk q of row r
    // sits at LDS pos q^(r&7); frag rows have r&7 == l15&7.
    const int x7  = l15 & 7;
    const int ch0 = (quad ^ x7) * 16;
    const int ch1 = ((quad + 4) ^ x7) * 16;

    for (int kk = 0; kk < D; kk += 64) {
        __syncthreads();                                 // prev iter's LDS reads done
        #pragma unroll
        for (int p = 0; p < 4; p++) {
            gload16(Ag + (size_t)(p * 8) * D + kk, la + (p * 8) * 64);
            gload16(Bg + (size_t)(p * 8) * D + kk, lb + (p * 8) * 64);
        }
        __syncthreads();                                 // vmcnt drain + tile ready
        #pragma unroll
        for (int ks = 0; ks < 2; ks++) {
            const int ch = ks ? ch1 : ch0;
            bf16x8 af[4], bfr[4];
            #pragma unroll
            for (int mi = 0; mi < 4; mi++)
                af[mi] = *(const bf16x8*)((const char*)sA + (wr * 64 + mi * 16 + l15) * 128 + ch);
            #pragma unroll
            for (int ni = 0; ni < 4; ni++)
                bfr[ni] = *(const bf16x8*)((const char*)sB + (wc * 64 + ni * 16 + l15) * 128 + ch);
            __builtin_amdgcn_s_setprio(1);
            #pragma unroll
            for (int mi = 0; mi < 4; mi++)
                #pragma unroll
                for (int ni = 0; ni < 4; ni++)
                    acc[mi][ni] = __builtin_amdgcn_mfma_f32_16x16x32_bf16(af[mi], bfr[ni], acc[mi][ni], 0, 0, 0);
            __builtin_amdgcn_s_setprio(0);
        }
    }

    // epilogue: 2 dump phases of 64 cols; 256 threads scan 2-per-row (32 cols each)
    unsigned bk[TOPK];
    #pragma unroll
    for (int s = 0; s < TOPK; s++) bk[s] = 0u;

    const int erow = t & 127, scb = (t >> 7) * 32;
    const int erx = erow & 31;                           // scan de-conflict XOR
    #pragma unroll
    for (int h = 0; h < 2; h++) {
        __syncthreads();
        if (wc == h) {
            #pragma unroll
            for (int ni = 0; ni < 4; ni++) {
                // inverted in-tile col -> quantized ties prefer SMALLER index
                unsigned pk = (unsigned)(127 - h * 64 - ni * 16 - l15);
                #pragma unroll
                for (int mi = 0; mi < 4; mi++) {
                    int colb = ni * 16 + l15;
                    int rowb = wr * 64 + mi * 16 + quad * 4;
                    f32x4 v = acc[mi][ni];
                    #pragma unroll
                    for (int r = 0; r < 4; r++) {  // swizzled slot: col ^ (row&31)
                        int rowg = rowb + r;
                        sK[rowg * 64 + (colb ^ (rowg & 31))] =
                            (__float_as_uint(v[r]) & 0xFFFFFF80u) | pk;
                    }
                }
            }
        }
        __syncthreads();
        // scan slots in per-lane XOR order: banks spread (2-way = free), and the
        // permutation is harmless — the key embeds the column; top-6 of the same
        // set is bit-identical.
        const unsigned* rowp = sK + erow * 64 + scb;
        #pragma unroll
        for (int c = 0; c < 32; c++) topk_insert_u(rowp[c ^ erx], bk);
    }

    // merge the two half-row scanners (mk aliases the dead score buffer;
    // stride 7 -> conflict-free)
    __syncthreads();
    if (t >= 128) {
        #pragma unroll
        for (int s = 0; s < TOPK; s++) mk[(t - 128) * 7 + s] = bk[s];
    }
    __syncthreads();
    if (t < 128) {
        #pragma unroll
        for (int s0 = 0; s0 < TOPK; s0++) topk_insert_u(mk[t * 7 + s0], bk);
        size_t o = ((size_t)(ri * 128 + t) * NT + ci) * TOPK;
        #pragma unroll
        for (int s = 0; s < TOPK; s++) {
            unsigned k = bk[s];
            candv[o + s] = __uint_as_float(k & 0xFFFFFF80u);   // quantized biased score
            candi[o + s] = ci * 128 + 127 - (int)(k & 127u);   // global column
        }
    }
}

// ------- fused merge (wave-parallel) + sparse loss + global atomic accumulate ----
// Unchanged from r17.
__global__ __launch_bounds__(256) void k_mergeloss(const float* __restrict__ candv,
                                                   const int* __restrict__ candi,
                                                   const float* __restrict__ hcn,
                                                   const float* __restrict__ sq,
                                                   const int* __restrict__ labp,
                                                   float* __restrict__ out) {
    __shared__ float bsum[4];
    const int w = threadIdx.x >> 6, lane = threadIdx.x & 63;
    const int i = blockIdx.x * 4 + w;

    const float* cv = candv + ((size_t)i * NT + lane) * TOPK;
    const int*   cj = candi + ((size_t)i * NT + lane) * TOPK;
    float bv[TOPK]; int bj[TOPK];
    #pragma unroll
    for (int s = 0; s < TOPK; s++) { bv[s] = cv[s]; bj[s] = cj[s]; }

    #pragma unroll
    for (int off = 1; off < 64; off <<= 1) {
        float pv[TOPK]; int pj[TOPK];
        #pragma unroll
        for (int s = 0; s < TOPK; s++) {
            pv[s] = __shfl_xor(bv[s], off, 64);
            pj[s] = __shfl_xor(bj[s], off, 64);
        }
        bool ilow = (lane & off) == 0;
        float av[TOPK], iv[TOPK]; int aj[TOPK], ij[TOPK];
        #pragma unroll
        for (int s = 0; s < TOPK; s++) {
            av[s] = ilow ? bv[s] : pv[s];  aj[s] = ilow ? bj[s] : pj[s];
            iv[s] = ilow ? pv[s] : bv[s];  ij[s] = ilow ? pj[s] : bj[s];
        }
        #pragma unroll
        for (int s = 0; s < TOPK; s++)
            if (iv[s] > av[TOPK - 1]) topk_insert(iv[s], ij[s], av, aj);
        #pragma unroll
        for (int s = 0; s < TOPK; s++) { bv[s] = av[s]; bj[s] = aj[s]; }
    }

    // loss: ranks 1..5 (rank 0 is self — biased self-score 5.0 is still max).
    const float* hi = hcn + (size_t)i * D;
    float4 h0 = *(const float4*)(hi + lane * 4);
    float4 h1 = *(const float4*)(hi + lane * 4 + 256);
    float4 h2 = *(const float4*)(hi + lane * 4 + 512);
    float sqi = sq[i];
    int li = labp[i];
    float part = 0.f;
    float base = 0.f;
    #pragma unroll
    for (int s = 1; s <= KNB; s++) {
        int j = bj[s];
        if (j >= BC) continue;
        const float* hj = hcn + (size_t)j * D;
        float4 g0 = *(const float4*)(hj + lane * 4);
        float4 g1 = *(const float4*)(hj + lane * 4 + 256);
        float4 g2 = *(const float4*)(hj + lane * 4 + 512);
        float d = h0.x * g0.x + h0.y * g0.y + h0.z * g0.z + h0.w * g0.w
                + h1.x * g1.x + h1.y * g1.y + h1.z * g1.z + h1.w * g1.w
                + h2.x * g2.x + h2.y * g2.y + h2.z * g2.z + h2.w * g2.w;
        float e = (li == labp[j]) ? 1.0f : -1.0f;
        part += e * (-2.0f) * d;
        if (lane == 0) base += e * (sqi + sq[j]);
    }
    part += base;
    #pragma unroll
    for (int off = 32; off; off >>= 1) part += __shfl_xor(part, off, 64);
    if (lane == 0) bsum[w] = part;
    __syncthreads();
    if (threadIdx.x == 0) {
        float s = bsum[0] + bsum[1] + bsum[2] + bsum[3];
        unsafeAtomicAdd(out, 0.5f * s / ((float)BC * (float)BC));
    }
}

extern "C" void kernel_launch(void* const* d_in, const int* in_sizes, int n_in,
                              void* d_out, int out_size, void* d_ws, size_t ws_size,
                              hipStream_t stream) {
    const float* hc   = (const float*)d_in[0];  // hidden_current  (4096,768)
    const float* hp   = (const float*)d_in[1];  // hidden_previous (8192,768)
    const int*   labp = (const int*)d_in[3];    // labels_previous (8192,)
    float* out = (float*)d_out;

    // workspace layout (~38 MB)
    unsigned short* hpnb = (unsigned short*)d_ws;          // BP*D bf16 (pre-swizzled)
    float* hcn  = (float*)(hpnb + (size_t)BP * D);         // BC*D f32
    float* sq   = hcn + (size_t)BC * D;                    // BC
    float* candv = sq + BC;                                // BC*NT*TOPK
    int*   candi = (int*)(candv + (size_t)BC * NT * TOPK); // BC*NT*TOPK

    k_norm<<<dim3(BP + BC), dim3(256), 0, stream>>>(hp, hc, hpnb, hcn, sq, out);
    k_simtop<<<dim3(2048), dim3(256), 0, stream>>>(hpnb, candv, candi);
    k_mergeloss<<<dim3(BC / 4), dim3(256), 0, stream>>>(candv, candi, hcn, sq, labp, out);
}

// Round 8
// 161.340 us; speedup vs baseline: 1.6911x; 1.0294x over previous
//
#include <hip/hip_runtime.h>

#define BC 4096      // rows of hidden_current
#define BP 8192      // rows of hidden_previous
#define D  768
#define KNB 5
#define TOPK 6
#define NT (BP / 128)   // 64 column tiles of the similarity matrix

typedef __bf16 bf16x8 __attribute__((ext_vector_type(8)));
typedef float  f32x4  __attribute__((ext_vector_type(4)));

__device__ __forceinline__ unsigned short f2bf(float f) {
    unsigned int u = __float_as_uint(f);
    u += 0x7fffu + ((u >> 16) & 1u);          // round-to-nearest-even
    return (unsigned short)(u >> 16);
}

__device__ __forceinline__ void gload16(const void* g, void* l) {
    __builtin_amdgcn_global_load_lds(
        (const __attribute__((address_space(1))) unsigned int*)g,
        (__attribute__((address_space(3))) unsigned int*)l, 16, 0, 0);
}

// Packed-key bubble insert (r17): bk[] sorted DESCENDING; one pass of pure
// v_max_u32/v_min_u32 (12 VOP2 ops, no cndmask). Keys unique (packed col bits).
__device__ __forceinline__ void topk_insert_u(unsigned v, unsigned* bk) {
    unsigned c = v;
    #pragma unroll
    for (int q = 0; q < TOPK; q++) {
        unsigned hi = (c > bk[q]) ? c : bk[q];   // v_max_u32
        c           = (c > bk[q]) ? bk[q] : c;   // v_min_u32
        bk[q] = hi;
    }
}

// ---------------- fused normalize: hp -> bf16 ranking copy, hc -> fp32 + sq ------
// r23: float4/ushort4 vectorized (16 B/lane loads, G13) on 192 active lanes.
// Values and memory layout bit-identical to the scalar version: hpnb keeps the
// PRE-SWIZZLE (16B chunk q of row r at chunk q^(r&7)); a float4 at element 4t
// stays inside one 8-element chunk, so the store address is just (4t)^rx.
__global__ __launch_bounds__(256) void k_norm(const float* __restrict__ hp,
                                              const float* __restrict__ hc,
                                              unsigned short* __restrict__ hpnb,
                                              float* __restrict__ hcn,
                                              float* __restrict__ sqout,
                                              float* __restrict__ out) {
    int b = blockIdx.x;
    int t = threadIdx.x;
    if (b == 0 && t == 0) out[0] = 0.0f;
    bool isP = (b < BP);
    int row = isP ? b : (b - BP);
    const float* xr = (isP ? hp : hc) + (size_t)row * D;
    float4 v = {0.f, 0.f, 0.f, 0.f};
    if (t < 192) v = *(const float4*)(xr + 4 * t);       // 768 = 192 lanes x 4
    float s = v.x * v.x + v.y * v.y + v.z * v.z + v.w * v.w;
    #pragma unroll
    for (int off = 32; off; off >>= 1) s += __shfl_xor(s, off, 64);
    __shared__ float wsum[4];
    if ((t & 63) == 0) wsum[t >> 6] = s;
    __syncthreads();
    float tot = wsum[0] + wsum[1] + wsum[2] + wsum[3];
    float rinv = 1.0f / fmaxf(sqrtf(tot), 1e-12f);
    if (t < 192) {
        if (isP) {
            ushort4 o4;
            o4.x = f2bf(v.x * rinv); o4.y = f2bf(v.y * rinv);
            o4.z = f2bf(v.z * rinv); o4.w = f2bf(v.w * rinv);
            int rx = (row & 7) << 3;                     // chunk swizzle (bits 3..5)
            *(ushort4*)(hpnb + (size_t)row * D + ((4 * t) ^ rx)) = o4;
        } else {
            float4 o = {v.x * rinv, v.y * rinv, v.z * rinv, v.w * rinv};
            *(float4*)(hcn + (size_t)row * D + 4 * t) = o;
            if (t == 0) sqout[row] = tot * rinv * rinv;
        }
    }
}

// ---------------- bf16 MFMA similarity tile + fused per-row top-6 ----------------
// r23: EXACT r17 kernel (proven 61.5 us). 2048 blocks, 128x128 tiles, +4.0 bias,
// packed-key epilogue, bubble min/max insert, super-tile XCD swizzle, padded
// [128][65] score buffer. Three structural variants (8-phase r18, symmetry
// r19/r20, 5-block LDS diet r21/r22) all measured worse — this is the keeper.
__global__ __launch_bounds__(256, 4) void k_simtop(const unsigned short* __restrict__ hp,
                                                   float* __restrict__ candv,
                                                   int* __restrict__ candi) {
    __shared__ char smem[36864];
    unsigned short* sA = (unsigned short*)smem;          // [128 rows][64 k] swizzled
    unsigned short* sB = sA + 128 * 64;
    unsigned* sK = (unsigned*)smem;                      // [128][65] packed keys (alias)
    unsigned* mk = (unsigned*)(smem + 33280);            // [128][7] partner top-6 keys

    const int t = threadIdx.x;
    const int l = t & 63;
    const int w = t >> 6;
    const int l15 = l & 15, quad = l >> 4;
    const int wr = w >> 1, wc = w & 1;

    // super-tile swizzle: xcd = b&7, slot = b>>3; super = (slot>>6)*8 + xcd
    int ri, ci;
    {
        int b = blockIdx.x;
        int super_id = (((b >> 9) & 3) << 3) | (b & 7);  // 0..31
        int within = (b >> 3) & 63;                       // 0..63
        ri = (super_id >> 3) * 8 + (within >> 3);         // 0..31
        ci = (super_id & 7) * 8 + (within & 7);           // 0..63
    }

    // per-lane global source: row group w*32 + p*8 + (l>>3), chunk l&7 (monotone)
    const int srow = l >> 3, sch = l & 7;
    const unsigned short* Ag = hp + (size_t)(ri * 128 + w * 32 + srow) * D + sch * 8;
    const unsigned short* Bg = hp + (size_t)(ci * 128 + w * 32 + srow) * D + sch * 8;
    unsigned short* la = sA + (w * 32) * 64;             // wave-uniform LDS bases
    unsigned short* lb = sB + (w * 32) * 64;

    // C-init = +4.0 bias: scores positive -> raw bits unsigned-compare monotone.
    f32x4 acc[4][4];
    #pragma unroll
    for (int i = 0; i < 4; i++)
        #pragma unroll
        for (int j = 0; j < 4; j++) acc[i][j] = (f32x4){4.f, 4.f, 4.f, 4.f};

    // fragment LDS chunk offsets (conflict-free): original k-chunk q of row r
    // sits at LDS pos q^(r&7); frag rows have r&7 == l15&7.
    const int x7  = l15 & 7;
    const int ch0 = (quad ^ x7) * 16;
    const int ch1 = ((quad + 4) ^ x7) * 16;

    for (int kk = 0; kk < D; kk += 64) {
        __syncthreads();                                 // prev iter's LDS reads done
        #pragma unroll
        for (int p = 0; p < 4; p++) {
            gload16(Ag + (size_t)(p * 8) * D + kk, la + (p * 8) * 64);
            gload16(Bg + (size_t)(p * 8) * D + kk, lb + (p * 8) * 64);
        }
        __syncthreads();                                 // vmcnt drain + tile ready
        #pragma unroll
        for (int ks = 0; ks < 2; ks++) {
            const int ch = ks ? ch1 : ch0;
            bf16x8 af[4], bfr[4];
            #pragma unroll
            for (int mi = 0; mi < 4; mi++)
                af[mi] = *(const bf16x8*)((const char*)sA + (wr * 64 + mi * 16 + l15) * 128 + ch);
            #pragma unroll
            for (int ni = 0; ni < 4; ni++)
                bfr[ni] = *(const bf16x8*)((const char*)sB + (wc * 64 + ni * 16 + l15) * 128 + ch);
            __builtin_amdgcn_s_setprio(1);
            #pragma unroll
            for (int mi = 0; mi < 4; mi++)
                #pragma unroll
                for (int ni = 0; ni < 4; ni++)
                    acc[mi][ni] = __builtin_amdgcn_mfma_f32_16x16x32_bf16(af[mi], bfr[ni], acc[mi][ni], 0, 0, 0);
            __builtin_amdgcn_s_setprio(0);
        }
    }

    // epilogue: 2 dump phases of 64 cols; 256 threads scan 2-per-row (32 cols each)
    unsigned bk[TOPK];
    #pragma unroll
    for (int s = 0; s < TOPK; s++) bk[s] = 0u;

    const int erow = t & 127, scb = (t >> 7) * 32;
    #pragma unroll
    for (int h = 0; h < 2; h++) {
        __syncthreads();
        if (wc == h) {
            #pragma unroll
            for (int ni = 0; ni < 4; ni++) {
                // inverted in-tile col -> quantized ties prefer SMALLER index
                unsigned pk = (unsigned)(127 - h * 64 - ni * 16 - l15);
                #pragma unroll
                for (int mi = 0; mi < 4; mi++) {
                    int colb = ni * 16 + l15;
                    int rowb = wr * 64 + mi * 16 + quad * 4;
                    f32x4 v = acc[mi][ni];
                    #pragma unroll
                    for (int r = 0; r < 4; r++)   // (bits & ~127) | pk : v_and_or_b32
                        sK[(rowb + r) * 65 + colb] =
                            (__float_as_uint(v[r]) & 0xFFFFFF80u) | pk;
                }
            }
        }
        __syncthreads();
        // branchless scan, 12-op bubble insert per value
        const unsigned* rowp = sK + erow * 65 + scb;
        #pragma unroll
        for (int c = 0; c < 32; c++) topk_insert_u(rowp[c], bk);
    }

    // merge the two half-row scanners (stride 7 -> conflict-free)
    __syncthreads();
    if (t >= 128) {
        #pragma unroll
        for (int s = 0; s < TOPK; s++) mk[(t - 128) * 7 + s] = bk[s];
    }
    __syncthreads();
    if (t < 128) {
        #pragma unroll
        for (int s0 = 0; s0 < TOPK; s0++) topk_insert_u(mk[t * 7 + s0], bk);
        size_t o = ((size_t)(ri * 128 + t) * NT + ci) * TOPK;
        #pragma unroll
        for (int s = 0; s < TOPK; s++) {
            unsigned k = bk[s];
            candv[o + s] = __uint_as_float(k & 0xFFFFFF80u);   // quantized biased score
            candi[o + s] = ci * 128 + 127 - (int)(k & 127u);   // global column
        }
    }
}

// ------- fused merge (wave-max pops) + sparse loss + global atomic accumulate ----
// r23: the old 6-round xor-merge (6 rounds x 6 x ~28-op float+int inserts ~ 1000
// VALU + 72 shfl per wave) is replaced by SIX WAVE-MAX POPS on u32 keys:
// candv bits are positive-float monotone, so compare as u32. Per pop: 6-step
// shfl_xor max + ballot(head==max) + lowest tied lane wins (= smallest tile =
// smallest j: EXACTLY the old incumbent-wins tie semantics) + shfl its index +
// that lane shifts its sorted list. ~26 ops/pop -> ~160 VALU + 42 cross-lane.
// Produces the identical ranked (key, j) sequence -> identical loss, same
// accumulation order.
__global__ __launch_bounds__(256) void k_mergeloss(const float* __restrict__ candv,
                                                   const int* __restrict__ candi,
                                                   const float* __restrict__ hcn,
                                                   const float* __restrict__ sq,
                                                   const int* __restrict__ labp,
                                                   float* __restrict__ out) {
    __shared__ float bsum[4];
    const int w = threadIdx.x >> 6, lane = threadIdx.x & 63;
    const int i = blockIdx.x * 4 + w;

    const unsigned* cv = (const unsigned*)candv + ((size_t)i * NT + lane) * TOPK;
    const int*      cj = candi + ((size_t)i * NT + lane) * TOPK;
    unsigned kv[TOPK]; int ji[TOPK];
    #pragma unroll
    for (int s = 0; s < TOPK; s++) { kv[s] = cv[s]; ji[s] = cj[s]; }

    int nbrj[TOPK];
    #pragma unroll
    for (int p = 0; p < TOPK; p++) {
        unsigned m = kv[0];
        #pragma unroll
        for (int off = 32; off; off >>= 1) {
            unsigned o = __shfl_xor(m, off, 64);
            m = (o > m) ? o : m;                         // v_max_u32
        }
        unsigned long long tied = __ballot(kv[0] == m);
        int src = __ffsll((unsigned long long)tied) - 1; // lowest lane = smallest tile
        nbrj[p] = __shfl(ji[0], src, 64);                // broadcast winner's index
        bool me = (lane == src);
        #pragma unroll
        for (int q = 0; q < TOPK - 1; q++) {             // winner pops its head
            kv[q] = me ? kv[q + 1] : kv[q];
            ji[q] = me ? ji[q + 1] : ji[q];
        }
        kv[TOPK - 1] = me ? 0u : kv[TOPK - 1];
    }

    // loss: ranks 1..5 (rank 0 is self — biased self-score 5.0 is the max).
    const float* hi = hcn + (size_t)i * D;
    float4 h0 = *(const float4*)(hi + lane * 4);
    float4 h1 = *(const float4*)(hi + lane * 4 + 256);
    float4 h2 = *(const float4*)(hi + lane * 4 + 512);
    float sqi = sq[i];
    int li = labp[i];
    float part = 0.f;          // per-lane: sum_s e_s * (-2) * dot_partial
    float base = 0.f;          // lane-0 only: sum_s e_s * (sqi + sqj)
    #pragma unroll
    for (int s = 1; s <= KNB; s++) {
        int j = nbrj[s];
        if (j >= BC) continue;
        const float* hj = hcn + (size_t)j * D;
        float4 g0 = *(const float4*)(hj + lane * 4);
        float4 g1 = *(const float4*)(hj + lane * 4 + 256);
        float4 g2 = *(const float4*)(hj + lane * 4 + 512);
        float d = h0.x * g0.x + h0.y * g0.y + h0.z * g0.z + h0.w * g0.w
                + h1.x * g1.x + h1.y * g1.y + h1.z * g1.z + h1.w * g1.w
                + h2.x * g2.x + h2.y * g2.y + h2.z * g2.z + h2.w * g2.w;
        float e = (li == labp[j]) ? 1.0f : -1.0f;
        part += e * (-2.0f) * d;
        if (lane == 0) base += e * (sqi + sq[j]);
    }
    part += base;              // only lane 0 carries base
    #pragma unroll
    for (int off = 32; off; off >>= 1) part += __shfl_xor(part, off, 64);
    if (lane == 0) bsum[w] = part;
    __syncthreads();
    if (threadIdx.x == 0) {
        float s = bsum[0] + bsum[1] + bsum[2] + bsum[3];
        unsafeAtomicAdd(out, 0.5f * s / ((float)BC * (float)BC));
    }
}

extern "C" void kernel_launch(void* const* d_in, const int* in_sizes, int n_in,
                              void* d_out, int out_size, void* d_ws, size_t ws_size,
                              hipStream_t stream) {
    const float* hc   = (const float*)d_in[0];  // hidden_current  (4096,768)
    const float* hp   = (const float*)d_in[1];  // hidden_previous (8192,768)
    const int*   labp = (const int*)d_in[3];    // labels_previous (8192,)
    float* out = (float*)d_out;

    // workspace layout (~38 MB)
    unsigned short* hpnb = (unsigned short*)d_ws;          // BP*D bf16 (pre-swizzled)
    float* hcn  = (float*)(hpnb + (size_t)BP * D);         // BC*D f32
    float* sq   = hcn + (size_t)BC * D;                    // BC
    float* candv = sq + BC;                                // BC*NT*TOPK
    int*   candi = (int*)(candv + (size_t)BC * NT * TOPK); // BC*NT*TOPK

    k_norm<<<dim3(BP + BC), dim3(256), 0, stream>>>(hp, hc, hpnb, hcn, sq, out);
    k_simtop<<<dim3(2048), dim3(256), 0, stream>>>(hpnb, candv, candi);
    k_mergeloss<<<dim3(BC / 4), dim3(256), 0, stream>>>(candv, candi, hcn, sq, labp, out);
}

// Round 10
// 157.851 us; speedup vs baseline: 1.7285x; 1.0221x over previous
//
#include <hip/hip_runtime.h>

#define BC 4096      // rows of hidden_current
#define BP 8192      // rows of hidden_previous
#define D  768
#define KNB 5
#define TOPK 6
#define NT (BP / 128)   // 64 column tiles of the similarity matrix

typedef __bf16 bf16x8 __attribute__((ext_vector_type(8)));
typedef float  f32x4  __attribute__((ext_vector_type(4)));

__device__ __forceinline__ unsigned short f2bf(float f) {
    unsigned int u = __float_as_uint(f);
    u += 0x7fffu + ((u >> 16) & 1u);          // round-to-nearest-even
    return (unsigned short)(u >> 16);
}

__device__ __forceinline__ void gload16(const void* g, void* l) {
    __builtin_amdgcn_global_load_lds(
        (const __attribute__((address_space(1))) unsigned int*)g,
        (__attribute__((address_space(3))) unsigned int*)l, 16, 0, 0);
}

// Packed-key bubble insert (r17): bk[] sorted DESCENDING; one pass of pure
// v_max_u32/v_min_u32 (12 VOP2 ops, no cndmask). Keys unique (packed col bits).
__device__ __forceinline__ void topk_insert_u(unsigned v, unsigned* bk) {
    unsigned c = v;
    #pragma unroll
    for (int q = 0; q < TOPK; q++) {
        unsigned hi = (c > bk[q]) ? c : bk[q];   // v_max_u32
        c           = (c > bk[q]) ? bk[q] : c;   // v_min_u32
        bk[q] = hi;
    }
}

// ---------------- fused normalize: hp -> bf16 ranking copy, hc -> fp32 + sq ------
// r24: WAVE-per-row (was block-per-row): 64 lanes x 12 elems, one 6-step shfl
// tree, no LDS, no barriers, no idle lanes; 3072 blocks (4 rows each, no
// hp/hc straddle: 8192 = 2048*4). hpnb keeps the PRE-SWIZZLE (16B chunk q of
// row r at chunk q^(r&7)); XOR only touches addr bits 3..5 so each ushort4
// store stays contiguous. Reassociated sum is fine: r23 changed the reduction
// order and absmax stayed 0.0.
__global__ __launch_bounds__(256) void k_norm(const float* __restrict__ hp,
                                              const float* __restrict__ hc,
                                              unsigned short* __restrict__ hpnb,
                                              float* __restrict__ hcn,
                                              float* __restrict__ sqout,
                                              float* __restrict__ out) {
    const int t = threadIdx.x;
    const int l = t & 63;
    const int row = blockIdx.x * 4 + (t >> 6);           // 0..12287
    if (blockIdx.x == 0 && t == 0) out[0] = 0.0f;
    const bool isP = (row < BP);
    const int r = isP ? row : row - BP;
    const float* xr = (isP ? hp : hc) + (size_t)r * D;
    float4 v0 = *(const float4*)(xr + 4 * l);
    float4 v1 = *(const float4*)(xr + 4 * l + 256);
    float4 v2 = *(const float4*)(xr + 4 * l + 512);
    float s = v0.x * v0.x + v0.y * v0.y + v0.z * v0.z + v0.w * v0.w
            + v1.x * v1.x + v1.y * v1.y + v1.z * v1.z + v1.w * v1.w
            + v2.x * v2.x + v2.y * v2.y + v2.z * v2.z + v2.w * v2.w;
    #pragma unroll
    for (int off = 32; off; off >>= 1) s += __shfl_xor(s, off, 64);
    float rinv = 1.0f / fmaxf(sqrtf(s), 1e-12f);
    if (isP) {
        unsigned short* yr = hpnb + (size_t)r * D;
        int rx = (r & 7) << 3;                           // chunk swizzle (bits 3..5)
        ushort4 a, b, c;
        a.x = f2bf(v0.x * rinv); a.y = f2bf(v0.y * rinv);
        a.z = f2bf(v0.z * rinv); a.w = f2bf(v0.w * rinv);
        b.x = f2bf(v1.x * rinv); b.y = f2bf(v1.y * rinv);
        b.z = f2bf(v1.z * rinv); b.w = f2bf(v1.w * rinv);
        c.x = f2bf(v2.x * rinv); c.y = f2bf(v2.y * rinv);
        c.z = f2bf(v2.z * rinv); c.w = f2bf(v2.w * rinv);
        *(ushort4*)(yr + ((4 * l) ^ rx))       = a;
        *(ushort4*)(yr + ((4 * l + 256) ^ rx)) = b;
        *(ushort4*)(yr + ((4 * l + 512) ^ rx)) = c;
    } else {
        float* yr = hcn + (size_t)r * D;
        *(float4*)(yr + 4 * l)       = (float4){v0.x * rinv, v0.y * rinv, v0.z * rinv, v0.w * rinv};
        *(float4*)(yr + 4 * l + 256) = (float4){v1.x * rinv, v1.y * rinv, v1.z * rinv, v1.w * rinv};
        *(float4*)(yr + 4 * l + 512) = (float4){v2.x * rinv, v2.y * rinv, v2.z * rinv, v2.w * rinv};
        if (l == 0) sqout[r] = s * rinv * rinv;
    }
}

// ---------------- bf16 MFMA similarity tile + fused per-row top-6 ----------------
// r24: EXACT r17 compute (proven 61.5-62.6 us; 8-phase r18, symmetry r19/r20,
// 5-block diet r21/r22 all measured worse). ONLY change: writeout is a single
// u32 key array (candi dropped — the key's low 7 bits encode the within-tile
// column and the tile index is the lane that owns the list in k_mergeloss).
// Halves candidate WRITE traffic (12.3 -> 6.2 MB).
__global__ __launch_bounds__(256, 4) void k_simtop(const unsigned short* __restrict__ hp,
                                                   unsigned* __restrict__ candk) {
    __shared__ char smem[36864];
    unsigned short* sA = (unsigned short*)smem;          // [128 rows][64 k] swizzled
    unsigned short* sB = sA + 128 * 64;
    unsigned* sK = (unsigned*)smem;                      // [128][65] packed keys (alias)
    unsigned* mk = (unsigned*)(smem + 33280);            // [128][7] partner top-6 keys

    const int t = threadIdx.x;
    const int l = t & 63;
    const int w = t >> 6;
    const int l15 = l & 15, quad = l >> 4;
    const int wr = w >> 1, wc = w & 1;

    // super-tile swizzle: xcd = b&7, slot = b>>3; super = (slot>>6)*8 + xcd
    int ri, ci;
    {
        int b = blockIdx.x;
        int super_id = (((b >> 9) & 3) << 3) | (b & 7);  // 0..31
        int within = (b >> 3) & 63;                       // 0..63
        ri = (super_id >> 3) * 8 + (within >> 3);         // 0..31
        ci = (super_id & 7) * 8 + (within & 7);           // 0..63
    }

    // per-lane global source: row group w*32 + p*8 + (l>>3), chunk l&7 (monotone)
    const int srow = l >> 3, sch = l & 7;
    const unsigned short* Ag = hp + (size_t)(ri * 128 + w * 32 + srow) * D + sch * 8;
    const unsigned short* Bg = hp + (size_t)(ci * 128 + w * 32 + srow) * D + sch * 8;
    unsigned short* la = sA + (w * 32) * 64;             // wave-uniform LDS bases
    unsigned short* lb = sB + (w * 32) * 64;

    // C-init = +4.0 bias: scores positive -> raw bits unsigned-compare monotone.
    f32x4 acc[4][4];
    #pragma unroll
    for (int i = 0; i < 4; i++)
        #pragma unroll
        for (int j = 0; j < 4; j++) acc[i][j] = (f32x4){4.f, 4.f, 4.f, 4.f};

    // fragment LDS chunk offsets (conflict-free): original k-chunk q of row r
    // sits at LDS pos q^(r&7); frag rows have r&7 == l15&7.
    const int x7  = l15 & 7;
    const int ch0 = (quad ^ x7) * 16;
    const int ch1 = ((quad + 4) ^ x7) * 16;

    for (int kk = 0; kk < D; kk += 64) {
        __syncthreads();                                 // prev iter's LDS reads done
        #pragma unroll
        for (int p = 0; p < 4; p++) {
            gload16(Ag + (size_t)(p * 8) * D + kk, la + (p * 8) * 64);
            gload16(Bg + (size_t)(p * 8) * D + kk, lb + (p * 8) * 64);
        }
        __syncthreads();                                 // vmcnt drain + tile ready
        #pragma unroll
        for (int ks = 0; ks < 2; ks++) {
            const int ch = ks ? ch1 : ch0;
            bf16x8 af[4], bfr[4];
            #pragma unroll
            for (int mi = 0; mi < 4; mi++)
                af[mi] = *(const bf16x8*)((const char*)sA + (wr * 64 + mi * 16 + l15) * 128 + ch);
            #pragma unroll
            for (int ni = 0; ni < 4; ni++)
                bfr[ni] = *(const bf16x8*)((const char*)sB + (wc * 64 + ni * 16 + l15) * 128 + ch);
            __builtin_amdgcn_s_setprio(1);
            #pragma unroll
            for (int mi = 0; mi < 4; mi++)
                #pragma unroll
                for (int ni = 0; ni < 4; ni++)
                    acc[mi][ni] = __builtin_amdgcn_mfma_f32_16x16x32_bf16(af[mi], bfr[ni], acc[mi][ni], 0, 0, 0);
            __builtin_amdgcn_s_setprio(0);
        }
    }

    // epilogue: 2 dump phases of 64 cols; 256 threads scan 2-per-row (32 cols each)
    unsigned bk[TOPK];
    #pragma unroll
    for (int s = 0; s < TOPK; s++) bk[s] = 0u;

    const int erow = t & 127, scb = (t >> 7) * 32;
    #pragma unroll
    for (int h = 0; h < 2; h++) {
        __syncthreads();
        if (wc == h) {
            #pragma unroll
            for (int ni = 0; ni < 4; ni++) {
                // inverted in-tile col -> quantized ties prefer SMALLER index
                unsigned pk = (unsigned)(127 - h * 64 - ni * 16 - l15);
                #pragma unroll
                for (int mi = 0; mi < 4; mi++) {
                    int colb = ni * 16 + l15;
                    int rowb = wr * 64 + mi * 16 + quad * 4;
                    f32x4 v = acc[mi][ni];
                    #pragma unroll
                    for (int r = 0; r < 4; r++)   // (bits & ~127) | pk : v_and_or_b32
                        sK[(rowb + r) * 65 + colb] =
                            (__float_as_uint(v[r]) & 0xFFFFFF80u) | pk;
                }
            }
        }
        __syncthreads();
        // branchless scan, 12-op bubble insert per value
        const unsigned* rowp = sK + erow * 65 + scb;
        #pragma unroll
        for (int c = 0; c < 32; c++) topk_insert_u(rowp[c], bk);
    }

    // merge the two half-row scanners (stride 7 -> conflict-free)
    __syncthreads();
    if (t >= 128) {
        #pragma unroll
        for (int s = 0; s < TOPK; s++) mk[(t - 128) * 7 + s] = bk[s];
    }
    __syncthreads();
    if (t < 128) {
        #pragma unroll
        for (int s0 = 0; s0 < TOPK; s0++) topk_insert_u(mk[t * 7 + s0], bk);
        size_t o = ((size_t)(ri * 128 + t) * NT + ci) * TOPK;
        #pragma unroll
        for (int s = 0; s < TOPK; s++) candk[o + s] = bk[s];   // key only (r24)
    }
}

// ------- fused merge (wave-max pops) + sparse loss + global atomic accumulate ----
// r24: key-only candidates. Per pop: 6-step shfl_xor u32-max + ballot + lowest
// tied lane (= smallest tile = smallest j: r17 tie semantics) — and the winner's
// global column comes straight from the reduced max: j = src*128 + 127 - (m&127).
// No candi array, no index shuffle. Produces the identical ranked j sequence.
__global__ __launch_bounds__(256) void k_mergeloss(const unsigned* __restrict__ candk,
                                                   const float* __restrict__ hcn,
                                                   const float* __restrict__ sq,
                                                   const int* __restrict__ labp,
                                                   float* __restrict__ out) {
    __shared__ float bsum[4];
    const int w = threadIdx.x >> 6, lane = threadIdx.x & 63;
    const int i = blockIdx.x * 4 + w;

    const unsigned* cv = candk + ((size_t)i * NT + lane) * TOPK;
    unsigned kv[TOPK];
    #pragma unroll
    for (int s = 0; s < TOPK; s++) kv[s] = cv[s];

    int nbrj[TOPK];
    #pragma unroll
    for (int p = 0; p < TOPK; p++) {
        unsigned m = kv[0];
        #pragma unroll
        for (int off = 32; off; off >>= 1) {
            unsigned o = __shfl_xor(m, off, 64);
            m = (o > m) ? o : m;                         // v_max_u32
        }
        unsigned long long tied = __ballot(kv[0] == m);
        int src = __ffsll((unsigned long long)tied) - 1; // lowest lane = smallest tile
        nbrj[p] = src * 128 + 127 - (int)(m & 127u);     // index from the key itself
        bool me = (lane == src);
        #pragma unroll
        for (int q = 0; q < TOPK - 1; q++)               // winner pops its head
            kv[q] = me ? kv[q + 1] : kv[q];
        kv[TOPK - 1] = me ? 0u : kv[TOPK - 1];
    }

    // loss: ranks 1..5 (rank 0 is self — biased self-score 5.0 is the max).
    const float* hi = hcn + (size_t)i * D;
    float4 h0 = *(const float4*)(hi + lane * 4);
    float4 h1 = *(const float4*)(hi + lane * 4 + 256);
    float4 h2 = *(const float4*)(hi + lane * 4 + 512);
    float sqi = sq[i];
    int li = labp[i];
    float part = 0.f;          // per-lane: sum_s e_s * (-2) * dot_partial
    float base = 0.f;          // lane-0 only: sum_s e_s * (sqi + sqj)
    #pragma unroll
    for (int s = 1; s <= KNB; s++) {
        int j = nbrj[s];
        if (j >= BC) continue;
        const float* hj = hcn + (size_t)j * D;
        float4 g0 = *(const float4*)(hj + lane * 4);
        float4 g1 = *(const float4*)(hj + lane * 4 + 256);
        float4 g2 = *(const float4*)(hj + lane * 4 + 512);
        float d = h0.x * g0.x + h0.y * g0.y + h0.z * g0.z + h0.w * g0.w
                + h1.x * g1.x + h1.y * g1.y + h1.z * g1.z + h1.w * g1.w
                + h2.x * g2.x + h2.y * g2.y + h2.z * g2.z + h2.w * g2.w;
        float e = (li == labp[j]) ? 1.0f : -1.0f;
        part += e * (-2.0f) * d;
        if (lane == 0) base += e * (sqi + sq[j]);
    }
    part += base;              // only lane 0 carries base
    #pragma unroll
    for (int off = 32; off; off >>= 1) part += __shfl_xor(part, off, 64);
    if (lane == 0) bsum[w] = part;
    __syncthreads();
    if (threadIdx.x == 0) {
        float s = bsum[0] + bsum[1] + bsum[2] + bsum[3];
        unsafeAtomicAdd(out, 0.5f * s / ((float)BC * (float)BC));
    }
}

extern "C" void kernel_launch(void* const* d_in, const int* in_sizes, int n_in,
                              void* d_out, int out_size, void* d_ws, size_t ws_size,
                              hipStream_t stream) {
    const float* hc   = (const float*)d_in[0];  // hidden_current  (4096,768)
    const float* hp   = (const float*)d_in[1];  // hidden_previous (8192,768)
    const int*   labp = (const int*)d_in[3];    // labels_previous (8192,)
    float* out = (float*)d_out;

    // workspace layout (~31 MB)
    unsigned short* hpnb = (unsigned short*)d_ws;          // BP*D bf16 (pre-swizzled)
    float* hcn  = (float*)(hpnb + (size_t)BP * D);         // BC*D f32
    float* sq   = hcn + (size_t)BC * D;                    // BC
    unsigned* candk = (unsigned*)(sq + BC);                // BC*NT*TOPK u32 keys

    k_norm<<<dim3((BP + BC) / 4), dim3(256), 0, stream>>>(hp, hc, hpnb, hcn, sq, out);
    k_simtop<<<dim3(2048), dim3(256), 0, stream>>>(hpnb, candk);
    k_mergeloss<<<dim3(BC / 4), dim3(256), 0, stream>>>(candk, hcn, sq, labp, out);
}

// Round 11
// 156.175 us; speedup vs baseline: 1.7470x; 1.0107x over previous
//
#include <hip/hip_runtime.h>

#define BC 4096      // rows of hidden_current
#define BP 8192      // rows of hidden_previous
#define D  768
#define KNB 5
#define TOPK 6
#define NT (BP / 128)   // 64 column tiles of the similarity matrix

typedef __bf16 bf16x8 __attribute__((ext_vector_type(8)));
typedef float  f32x4  __attribute__((ext_vector_type(4)));

__device__ __forceinline__ unsigned short f2bf(float f) {
    unsigned int u = __float_as_uint(f);
    u += 0x7fffu + ((u >> 16) & 1u);          // round-to-nearest-even
    return (unsigned short)(u >> 16);
}

__device__ __forceinline__ void gload16(const void* g, void* l) {
    __builtin_amdgcn_global_load_lds(
        (const __attribute__((address_space(1))) unsigned int*)g,
        (__attribute__((address_space(3))) unsigned int*)l, 16, 0, 0);
}

// Packed-key bubble insert (r17): bk[] sorted DESCENDING; one pass of pure
// v_max_u32/v_min_u32 (12 VOP2 ops, no cndmask). Keys unique (packed col bits).
__device__ __forceinline__ void topk_insert_u(unsigned v, unsigned* bk) {
    unsigned c = v;
    #pragma unroll
    for (int q = 0; q < TOPK; q++) {
        unsigned hi = (c > bk[q]) ? c : bk[q];   // v_max_u32
        c           = (c > bk[q]) ? bk[q] : c;   // v_min_u32
        bk[q] = hi;
    }
}

// ---------------- hp normalize -> bf16 ranking copy (pre-swizzled) ---------------
// r25: hp-ONLY (the hc pass is folded into k_mergeloss — hcn/sq arrays deleted).
// Wave-per-row, 2048 blocks x 4 rows. hpnb keeps the PRE-SWIZZLE (16B chunk q of
// row r at chunk q^(r&7)); XOR only touches addr bits 3..5 so each ushort4 store
// stays contiguous. Reassociated norm sum is ulp-safe (r23/r24 changed reduction
// order; absmax stayed 0.0).
__global__ __launch_bounds__(256) void k_norm(const float* __restrict__ hp,
                                              unsigned short* __restrict__ hpnb,
                                              float* __restrict__ out) {
    const int t = threadIdx.x;
    const int l = t & 63;
    const int r = blockIdx.x * 4 + (t >> 6);             // 0..8191
    if (blockIdx.x == 0 && t == 0) out[0] = 0.0f;
    const float* xr = hp + (size_t)r * D;
    float4 v0 = *(const float4*)(xr + 4 * l);
    float4 v1 = *(const float4*)(xr + 4 * l + 256);
    float4 v2 = *(const float4*)(xr + 4 * l + 512);
    float s = v0.x * v0.x + v0.y * v0.y + v0.z * v0.z + v0.w * v0.w
            + v1.x * v1.x + v1.y * v1.y + v1.z * v1.z + v1.w * v1.w
            + v2.x * v2.x + v2.y * v2.y + v2.z * v2.z + v2.w * v2.w;
    #pragma unroll
    for (int off = 32; off; off >>= 1) s += __shfl_xor(s, off, 64);
    float rinv = 1.0f / fmaxf(sqrtf(s), 1e-12f);
    unsigned short* yr = hpnb + (size_t)r * D;
    int rx = (r & 7) << 3;                               // chunk swizzle (bits 3..5)
    ushort4 a, b, c;
    a.x = f2bf(v0.x * rinv); a.y = f2bf(v0.y * rinv);
    a.z = f2bf(v0.z * rinv); a.w = f2bf(v0.w * rinv);
    b.x = f2bf(v1.x * rinv); b.y = f2bf(v1.y * rinv);
    b.z = f2bf(v1.z * rinv); b.w = f2bf(v1.w * rinv);
    c.x = f2bf(v2.x * rinv); c.y = f2bf(v2.y * rinv);
    c.z = f2bf(v2.z * rinv); c.w = f2bf(v2.w * rinv);
    *(ushort4*)(yr + ((4 * l) ^ rx))       = a;
    *(ushort4*)(yr + ((4 * l + 256) ^ rx)) = b;
    *(ushort4*)(yr + ((4 * l + 512) ^ rx)) = c;
}

// ---------------- bf16 MFMA similarity tile + fused per-row top-6 ----------------
// UNCHANGED from r24 (61.5-62.6 us across 4 runs; structural ceiling verified by
// three falsified alternatives: 8-phase r18, symmetry r19/r20, 5-block r21/r22).
// Key-only writeout: the u32 key embeds the within-tile column (low 7 bits);
// the tile index is the lane that owns the list in k_mergeloss.
__global__ __launch_bounds__(256, 4) void k_simtop(const unsigned short* __restrict__ hp,
                                                   unsigned* __restrict__ candk) {
    __shared__ char smem[36864];
    unsigned short* sA = (unsigned short*)smem;          // [128 rows][64 k] swizzled
    unsigned short* sB = sA + 128 * 64;
    unsigned* sK = (unsigned*)smem;                      // [128][65] packed keys (alias)
    unsigned* mk = (unsigned*)(smem + 33280);            // [128][7] partner top-6 keys

    const int t = threadIdx.x;
    const int l = t & 63;
    const int w = t >> 6;
    const int l15 = l & 15, quad = l >> 4;
    const int wr = w >> 1, wc = w & 1;

    // super-tile swizzle: xcd = b&7, slot = b>>3; super = (slot>>6)*8 + xcd
    int ri, ci;
    {
        int b = blockIdx.x;
        int super_id = (((b >> 9) & 3) << 3) | (b & 7);  // 0..31
        int within = (b >> 3) & 63;                       // 0..63
        ri = (super_id >> 3) * 8 + (within >> 3);         // 0..31
        ci = (super_id & 7) * 8 + (within & 7);           // 0..63
    }

    // per-lane global source: row group w*32 + p*8 + (l>>3), chunk l&7 (monotone)
    const int srow = l >> 3, sch = l & 7;
    const unsigned short* Ag = hp + (size_t)(ri * 128 + w * 32 + srow) * D + sch * 8;
    const unsigned short* Bg = hp + (size_t)(ci * 128 + w * 32 + srow) * D + sch * 8;
    unsigned short* la = sA + (w * 32) * 64;             // wave-uniform LDS bases
    unsigned short* lb = sB + (w * 32) * 64;

    // C-init = +4.0 bias: scores positive -> raw bits unsigned-compare monotone.
    f32x4 acc[4][4];
    #pragma unroll
    for (int i = 0; i < 4; i++)
        #pragma unroll
        for (int j = 0; j < 4; j++) acc[i][j] = (f32x4){4.f, 4.f, 4.f, 4.f};

    // fragment LDS chunk offsets (conflict-free): original k-chunk q of row r
    // sits at LDS pos q^(r&7); frag rows have r&7 == l15&7.
    const int x7  = l15 & 7;
    const int ch0 = (quad ^ x7) * 16;
    const int ch1 = ((quad + 4) ^ x7) * 16;

    for (int kk = 0; kk < D; kk += 64) {
        __syncthreads();                                 // prev iter's LDS reads done
        #pragma unroll
        for (int p = 0; p < 4; p++) {
            gload16(Ag + (size_t)(p * 8) * D + kk, la + (p * 8) * 64);
            gload16(Bg + (size_t)(p * 8) * D + kk, lb + (p * 8) * 64);
        }
        __syncthreads();                                 // vmcnt drain + tile ready
        #pragma unroll
        for (int ks = 0; ks < 2; ks++) {
            const int ch = ks ? ch1 : ch0;
            bf16x8 af[4], bfr[4];
            #pragma unroll
            for (int mi = 0; mi < 4; mi++)
                af[mi] = *(const bf16x8*)((const char*)sA + (wr * 64 + mi * 16 + l15) * 128 + ch);
            #pragma unroll
            for (int ni = 0; ni < 4; ni++)
                bfr[ni] = *(const bf16x8*)((const char*)sB + (wc * 64 + ni * 16 + l15) * 128 + ch);
            __builtin_amdgcn_s_setprio(1);
            #pragma unroll
            for (int mi = 0; mi < 4; mi++)
                #pragma unroll
                for (int ni = 0; ni < 4; ni++)
                    acc[mi][ni] = __builtin_amdgcn_mfma_f32_16x16x32_bf16(af[mi], bfr[ni], acc[mi][ni], 0, 0, 0);
            __builtin_amdgcn_s_setprio(0);
        }
    }

    // epilogue: 2 dump phases of 64 cols; 256 threads scan 2-per-row (32 cols each)
    unsigned bk[TOPK];
    #pragma unroll
    for (int s = 0; s < TOPK; s++) bk[s] = 0u;

    const int erow = t & 127, scb = (t >> 7) * 32;
    #pragma unroll
    for (int h = 0; h < 2; h++) {
        __syncthreads();
        if (wc == h) {
            #pragma unroll
            for (int ni = 0; ni < 4; ni++) {
                // inverted in-tile col -> quantized ties prefer SMALLER index
                unsigned pk = (unsigned)(127 - h * 64 - ni * 16 - l15);
                #pragma unroll
                for (int mi = 0; mi < 4; mi++) {
                    int colb = ni * 16 + l15;
                    int rowb = wr * 64 + mi * 16 + quad * 4;
                    f32x4 v = acc[mi][ni];
                    #pragma unroll
                    for (int r = 0; r < 4; r++)   // (bits & ~127) | pk : v_and_or_b32
                        sK[(rowb + r) * 65 + colb] =
                            (__float_as_uint(v[r]) & 0xFFFFFF80u) | pk;
                }
            }
        }
        __syncthreads();
        // branchless scan, 12-op bubble insert per value
        const unsigned* rowp = sK + erow * 65 + scb;
        #pragma unroll
        for (int c = 0; c < 32; c++) topk_insert_u(rowp[c], bk);
    }

    // merge the two half-row scanners (stride 7 -> conflict-free)
    __syncthreads();
    if (t >= 128) {
        #pragma unroll
        for (int s = 0; s < TOPK; s++) mk[(t - 128) * 7 + s] = bk[s];
    }
    __syncthreads();
    if (t < 128) {
        #pragma unroll
        for (int s0 = 0; s0 < TOPK; s0++) topk_insert_u(mk[t * 7 + s0], bk);
        size_t o = ((size_t)(ri * 128 + t) * NT + ci) * TOPK;
        #pragma unroll
        for (int s = 0; s < TOPK; s++) candk[o + s] = bk[s];   // key only
    }
}

// ------- fused merge + ON-THE-FLY hc normalize + sparse loss + atomic -----------
// r25: hc normalization folded in (hcn/sq arrays deleted). The neighbor-dot
// row reads were already happening — the norm comes almost free: accumulate
// sum(g*g) alongside the dot partials, one extra 6-shfl wave reduce per
// neighbor, then scale the per-lane dot partial by rinv_i*rinv_j (deferred
// reduction unchanged). sq_i -> sraw*rinv^2 (== sum(hcn^2) up to ulps; ulp
// robustness established empirically in r23/r24: rinv's reduction order changed
// and absmax stayed 0.0).
// Merge: wave-max pops on u32 keys; winner's global column decoded from the
// reduced max itself: j = src*128 + 127 - (m&127); lowest tied lane = smallest
// tile = smallest j (r17 tie semantics).
__global__ __launch_bounds__(256) void k_mergeloss(const unsigned* __restrict__ candk,
                                                   const float* __restrict__ hc,
                                                   const int* __restrict__ labp,
                                                   float* __restrict__ out) {
    __shared__ float bsum[4];
    const int w = threadIdx.x >> 6, lane = threadIdx.x & 63;
    const int i = blockIdx.x * 4 + w;

    const unsigned* cv = candk + ((size_t)i * NT + lane) * TOPK;
    unsigned kv[TOPK];
    #pragma unroll
    for (int s = 0; s < TOPK; s++) kv[s] = cv[s];

    int nbrj[TOPK];
    #pragma unroll
    for (int p = 0; p < TOPK; p++) {
        unsigned m = kv[0];
        #pragma unroll
        for (int off = 32; off; off >>= 1) {
            unsigned o = __shfl_xor(m, off, 64);
            m = (o > m) ? o : m;                         // v_max_u32
        }
        unsigned long long tied = __ballot(kv[0] == m);
        int src = __ffsll((unsigned long long)tied) - 1; // lowest lane = smallest tile
        nbrj[p] = src * 128 + 127 - (int)(m & 127u);     // index from the key itself
        bool me = (lane == src);
        #pragma unroll
        for (int q = 0; q < TOPK - 1; q++)               // winner pops its head
            kv[q] = me ? kv[q + 1] : kv[q];
        kv[TOPK - 1] = me ? 0u : kv[TOPK - 1];
    }

    // loss over ranks 1..5 (rank 0 is self — biased self-score 5.0 is the max).
    const float* hi = hc + (size_t)i * D;
    float4 h0 = *(const float4*)(hi + lane * 4);
    float4 h1 = *(const float4*)(hi + lane * 4 + 256);
    float4 h2 = *(const float4*)(hi + lane * 4 + 512);
    float sp = h0.x * h0.x + h0.y * h0.y + h0.z * h0.z + h0.w * h0.w
             + h1.x * h1.x + h1.y * h1.y + h1.z * h1.z + h1.w * h1.w
             + h2.x * h2.x + h2.y * h2.y + h2.z * h2.z + h2.w * h2.w;
    #pragma unroll
    for (int off = 32; off; off >>= 1) sp += __shfl_xor(sp, off, 64);
    const float rinv_i = 1.0f / fmaxf(sqrtf(sp), 1e-12f);
    const float sqn_i  = sp * rinv_i * rinv_i;           // == sum(hcn_i^2) up to ulps
    const int li = labp[i];

    float part = 0.f;          // per-lane: sum_s e_s * (-2 rinv_i rinv_j) * dotraw
    float base = 0.f;          // lane-0 only: sum_s e_s * (sqn_i + sqn_j)
    #pragma unroll
    for (int s = 1; s <= KNB; s++) {
        int j = nbrj[s];                                 // wave-uniform
        if (j >= BC) continue;
        const float* hj = hc + (size_t)j * D;
        float4 g0 = *(const float4*)(hj + lane * 4);
        float4 g1 = *(const float4*)(hj + lane * 4 + 256);
        float4 g2 = *(const float4*)(hj + lane * 4 + 512);
        float d = h0.x * g0.x + h0.y * g0.y + h0.z * g0.z + h0.w * g0.w
                + h1.x * g1.x + h1.y * g1.y + h1.z * g1.z + h1.w * g1.w
                + h2.x * g2.x + h2.y * g2.y + h2.z * g2.z + h2.w * g2.w;
        float gq = g0.x * g0.x + g0.y * g0.y + g0.z * g0.z + g0.w * g0.w
                 + g1.x * g1.x + g1.y * g1.y + g1.z * g1.z + g1.w * g1.w
                 + g2.x * g2.x + g2.y * g2.y + g2.z * g2.z + g2.w * g2.w;
        #pragma unroll
        for (int off = 32; off; off >>= 1) gq += __shfl_xor(gq, off, 64);
        float rinv_j = 1.0f / fmaxf(sqrtf(gq), 1e-12f);
        float e = (li == labp[j]) ? 1.0f : -1.0f;
        part += e * (-2.0f * rinv_i * rinv_j) * d;       // deferred per-lane partial
        if (lane == 0) base += e * (sqn_i + gq * rinv_j * rinv_j);
    }
    part += base;              // only lane 0 carries base
    #pragma unroll
    for (int off = 32; off; off >>= 1) part += __shfl_xor(part, off, 64);
    if (lane == 0) bsum[w] = part;
    __syncthreads();
    if (threadIdx.x == 0) {
        float s = bsum[0] + bsum[1] + bsum[2] + bsum[3];
        unsafeAtomicAdd(out, 0.5f * s / ((float)BC * (float)BC));
    }
}

extern "C" void kernel_launch(void* const* d_in, const int* in_sizes, int n_in,
                              void* d_out, int out_size, void* d_ws, size_t ws_size,
                              hipStream_t stream) {
    const float* hc   = (const float*)d_in[0];  // hidden_current  (4096,768)
    const float* hp   = (const float*)d_in[1];  // hidden_previous (8192,768)
    const int*   labp = (const int*)d_in[3];    // labels_previous (8192,)
    float* out = (float*)d_out;

    // workspace layout (~19 MB)
    unsigned short* hpnb = (unsigned short*)d_ws;          // BP*D bf16 (pre-swizzled)
    unsigned* candk = (unsigned*)(hpnb + (size_t)BP * D);  // BC*NT*TOPK u32 keys

    k_norm<<<dim3(BP / 4), dim3(256), 0, stream>>>(hp, hpnb, out);
    k_simtop<<<dim3(2048), dim3(256), 0, stream>>>(hpnb, candk);
    k_mergeloss<<<dim3(BC / 4), dim3(256), 0, stream>>>(candk, hc, labp, out);
}